// Round 7
// baseline (135.531 us; speedup 1.0000x reference)
//
#include <hip/hip_runtime.h>
#include <hip/hip_bf16.h>
#include <math.h>

// Problem: B=1, T=2048, E=1024, H=16, DH=64, NB=10, ML=2048
// Pipeline (all bf16 MFMA):
//   Xb = bf16(X); WbT = [Wq*0.125|Wk|Wv|Wr]^T bf16; WpT = Wp^T bf16
//   Y[2048][3328] = Xb @ Wb + bias   (Q|K|V|R)
//   Vt[h][64][2048] = V^T per head; BndT[2176][32] zero-padded bf16 band table
//     (aliased into WbT, dead after the projection GEMM)
//   AO = flash-attention (swapped-operand MFMA, in-register softmax,
//        K/V double-buffer w/ 1 barrier/iter, early BndT, defer-max)
//   out = AO @ Wp + bp (f32)

typedef __attribute__((ext_vector_type(8))) short bf16x8;
typedef __attribute__((ext_vector_type(4))) float f32x4;

#define MFMA16(a,b,c) __builtin_amdgcn_mfma_f32_16x16x32_bf16((a),(b),(c),0,0,0)
#define GLB(p)  ((const __attribute__((address_space(1))) void*)(p))
#define LDSP(p) ((__attribute__((address_space(3))) void*)(p))
#define LDY2 3328

__device__ __forceinline__ unsigned short f2bf(float x){
  unsigned u = __float_as_uint(x);
  u = (u + 0x7FFFu + ((u >> 16) & 1u)) >> 16;
  return (unsigned short)u;
}
__device__ __forceinline__ unsigned short f2bf_rn(float x){
  __hip_bfloat16 b = __float2bfloat16(x);
  return *reinterpret_cast<unsigned short*>(&b);
}

// ---------------- prep kernels ----------------

__global__ __launch_bounds__(256) void convert_x(const float* __restrict__ X,
                                                 unsigned short* __restrict__ Xb){
  const int i = (blockIdx.x * 256 + threadIdx.x) * 8;
  f32x4 a = *(const f32x4*)(X + i);
  f32x4 b = *(const f32x4*)(X + i + 4);
  bf16x8 v;
  v[0]=(short)f2bf(a.x); v[1]=(short)f2bf(a.y); v[2]=(short)f2bf(a.z); v[3]=(short)f2bf(a.w);
  v[4]=(short)f2bf(b.x); v[5]=(short)f2bf(b.y); v[6]=(short)f2bf(b.z); v[7]=(short)f2bf(b.w);
  *(bf16x8*)(Xb + i) = v;
}

// WbT[c][k]; Q columns prescaled by 1/sqrt(d)=0.125
__global__ __launch_bounds__(256) void pack_wbt(const float* __restrict__ Wq,
    const float* __restrict__ Wk, const float* __restrict__ Wv,
    const float* __restrict__ Wr, unsigned short* __restrict__ WbT){
  __shared__ float tile[64][65];
  const int k0 = blockIdx.x * 64, c0 = blockIdx.y * 64;
  const int tid = threadIdx.x;
  {
    const int r = tid >> 2, cs = (tid & 3) << 4;
    #pragma unroll
    for (int q = 0; q < 4; ++q){
      const int c = c0 + cs + q * 4;
      f32x4 v;
      if (c < 1024){
        v = *(const f32x4*)(Wq + (size_t)(k0+r)*1024 + c);
        v.x *= 0.125f; v.y *= 0.125f; v.z *= 0.125f; v.w *= 0.125f;
      }
      else if (c < 2048) v = *(const f32x4*)(Wk + (size_t)(k0+r)*1024 + (c-1024));
      else if (c < 3072) v = *(const f32x4*)(Wv + (size_t)(k0+r)*1024 + (c-2048));
      else if (c < 3232) v = *(const f32x4*)(Wr + (size_t)(k0+r)*160  + (c-3072));
      else               v = (f32x4){0.f,0.f,0.f,0.f};
      tile[r][cs+q*4+0]=v.x; tile[r][cs+q*4+1]=v.y; tile[r][cs+q*4+2]=v.z; tile[r][cs+q*4+3]=v.w;
    }
  }
  __syncthreads();
  const int c = tid >> 2, ks = (tid & 3) << 4;
  bf16x8 o0, o1;
  #pragma unroll
  for (int x = 0; x < 8; ++x) o0[x] = (short)f2bf(tile[ks + x][c]);
  #pragma unroll
  for (int x = 0; x < 8; ++x) o1[x] = (short)f2bf(tile[ks + 8 + x][c]);
  *(bf16x8*)(WbT + (size_t)(c0 + c) * 1024 + k0 + ks)     = o0;
  *(bf16x8*)(WbT + (size_t)(c0 + c) * 1024 + k0 + ks + 8) = o1;
}

__global__ __launch_bounds__(256) void transpose_wp(const float* __restrict__ Wp,
                                                    unsigned short* __restrict__ WpT){
  __shared__ float tile[64][65];
  const int k0 = blockIdx.x * 64, c0 = blockIdx.y * 64;
  const int tid = threadIdx.x;
  {
    const int r = tid >> 2, cs = (tid & 3) << 4;
    #pragma unroll
    for (int q = 0; q < 4; ++q){
      f32x4 v = *(const f32x4*)(Wp + (size_t)(k0+r)*1024 + c0 + cs + q*4);
      tile[r][cs+q*4+0]=v.x; tile[r][cs+q*4+1]=v.y; tile[r][cs+q*4+2]=v.z; tile[r][cs+q*4+3]=v.w;
    }
  }
  __syncthreads();
  const int c = tid >> 2, ks = (tid & 3) << 4;
  bf16x8 o0, o1;
  #pragma unroll
  for (int x = 0; x < 8; ++x) o0[x] = (short)f2bf(tile[ks + x][c]);
  #pragma unroll
  for (int x = 0; x < 8; ++x) o1[x] = (short)f2bf(tile[ks + 8 + x][c]);
  *(bf16x8*)(WpT + (size_t)(c0 + c) * 1024 + k0 + ks)     = o0;
  *(bf16x8*)(WpT + (size_t)(c0 + c) * 1024 + k0 + ks + 8) = o1;
}

__global__ void build_bias(const float* __restrict__ bq, const float* __restrict__ br,
                           float* __restrict__ bias){
  const int c = blockIdx.x * 256 + threadIdx.x;
  if (c >= 3328) return;
  float v = 0.f;
  if (c < 1024) v = bq[c] * 0.125f;
  else if (c >= 3072 && c < 3232) v = br[c - 3072];
  bias[c] = v;
}

// Vt[h][d][t] <- Y[t][2048 + h*64 + d]
__global__ __launch_bounds__(256) void vt_transpose(const unsigned short* __restrict__ Y,
                                                    unsigned short* __restrict__ Vt){
  __shared__ unsigned short tile[64][72];
  const int h = blockIdx.y, t0 = blockIdx.x * 64;
  const int tid = threadIdx.x;
  {
    const int r = tid >> 2, cs = (tid & 3) << 4;
    const unsigned short* src = Y + (size_t)(t0 + r) * LDY2 + 2048 + h * 64 + cs;
    *(bf16x8*)&tile[r][cs]     = *(const bf16x8*)src;
    *(bf16x8*)&tile[r][cs + 8] = *(const bf16x8*)(src + 8);
  }
  __syncthreads();
  const int d = tid >> 2, ts = (tid & 3) << 4;
  bf16x8 o0, o1;
  #pragma unroll
  for (int x = 0; x < 8; ++x) o0[x] = (short)tile[ts + x][d];
  #pragma unroll
  for (int x = 0; x < 8; ++x) o1[x] = (short)tile[ts + 8 + x][d];
  *(bf16x8*)(Vt + (size_t)(h*64 + d) * 2048 + t0 + ts)     = o0;
  *(bf16x8*)(Vt + (size_t)(h*64 + d) * 2048 + t0 + ts + 8) = o1;
}

// BndT[t'][32]: t' = rel + 64, t' in [0,2176); cols n<10 = bnd[n][rel], else 0
__global__ __launch_bounds__(256) void build_bndt(const float* __restrict__ bnd,
                                                  unsigned short* __restrict__ BndT){
  const int t = blockIdx.x * 256 + threadIdx.x;
  if (t >= 2176) return;
  const int rel = t - 64;
  unsigned short* dst = BndT + (size_t)t * 32;
  bf16x8 v0 = {}, v1 = {}, z = {};
  if (rel >= 0 && rel < 2048){
    #pragma unroll
    for (int n = 0; n < 8; ++n) v0[n] = (short)f2bf(bnd[n * 2048 + rel]);
    v1[0] = (short)f2bf(bnd[8 * 2048 + rel]);
    v1[1] = (short)f2bf(bnd[9 * 2048 + rel]);
  }
  *(bf16x8*)dst        = v0;
  *(bf16x8*)(dst + 8)  = v1;
  *(bf16x8*)(dst + 16) = z;
  *(bf16x8*)(dst + 24) = z;
}

// ---------------- bf16 MFMA GEMM (m97 structure) ----------------

__global__ __launch_bounds__(256) void gemm_bf16(
    const unsigned short* __restrict__ A,
    const unsigned short* __restrict__ BT,
    const float* __restrict__ bias,
    void* __restrict__ C, int ldc, int out_f32)
{
  __shared__ unsigned short As[128 * 64];
  __shared__ unsigned short Bs[128 * 64];
  const int tid = threadIdx.x;
  const int w = tid >> 6, lane = tid & 63;
  const int lid = lane & 15, lgrp = lane >> 4;
  const int wm = w >> 1, wn = w & 1;
  const int row0 = blockIdx.y << 7, col0 = blockIdx.x << 7;
  const int sr = lane >> 3;
  const int sc = (lane & 7) ^ sr;

  f32x4 acc[4][4] = {};

  for (int k0 = 0; k0 < 1024; k0 += 64){
    #pragma unroll
    for (int it = 0; it < 4; ++it){
      const int r0w = (w << 5) + (it << 3);
      const int r = r0w + sr;
      __builtin_amdgcn_global_load_lds(GLB(A  + (size_t)(row0 + r) * 1024 + k0 + (sc << 3)),
                                       LDSP(&As[r0w << 6]), 16, 0, 0);
      __builtin_amdgcn_global_load_lds(GLB(BT + (size_t)(col0 + r) * 1024 + k0 + (sc << 3)),
                                       LDSP(&Bs[r0w << 6]), 16, 0, 0);
    }
    __syncthreads();

    bf16x8 af[4][2], bfr[4][2];
    #pragma unroll
    for (int m = 0; m < 4; ++m){
      const int ra = wm * 64 + m * 16 + lid;
      const int rb = wn * 64 + m * 16 + lid;
      #pragma unroll
      for (int kk = 0; kk < 2; ++kk){
        const int kc = kk * 4 + lgrp;
        af[m][kk]  = *(const bf16x8*)&As[(ra << 6) + ((kc ^ (lid & 7)) << 3)];
        bfr[m][kk] = *(const bf16x8*)&Bs[(rb << 6) + ((kc ^ (lid & 7)) << 3)];
      }
    }
    #pragma unroll
    for (int m = 0; m < 4; ++m)
      #pragma unroll
      for (int n = 0; n < 4; ++n){
        acc[m][n] = MFMA16(af[m][0], bfr[n][0], acc[m][n]);
        acc[m][n] = MFMA16(af[m][1], bfr[n][1], acc[m][n]);
      }
    __syncthreads();
  }

  #pragma unroll
  for (int m = 0; m < 4; ++m){
    #pragma unroll
    for (int n = 0; n < 4; ++n){
      const int col = col0 + wn * 64 + n * 16 + lid;
      const float bv = bias[col];
      #pragma unroll
      for (int i = 0; i < 4; ++i){
        const int row = row0 + wm * 64 + m * 16 + lgrp * 4 + i;
        const float v = acc[m][n][i] + bv;
        if (out_f32) ((float*)C)[(size_t)row * ldc + col] = v;
        else ((unsigned short*)C)[(size_t)row * ldc + col] = f2bf(v);
      }
    }
  }
}

// ---------------- fused flash attention (swapped-operand MFMA) ----------------
// Wave owns 16 q-rows (q = q0 + w*16 + lid). S^T = mfma(K,Q): lane holds
// S[q=lid][16 j-vals]. In-register online softmax; defer-max (THR=8).
// K/V double-buffered, 1 barrier per iter; BndT loads issued before S-MFMAs.
// E-window LDS layout: el[r][c], c in [0,80), rel(c) = d0 + w*16 + c - 63.

__global__ __launch_bounds__(256) void attn_mfma(
    const unsigned short* __restrict__ Y,
    const unsigned short* __restrict__ Vt,
    const unsigned short* __restrict__ BndT,
    unsigned short* __restrict__ AO)
{
  __shared__ unsigned short Ks[2][64 * 64]; // [j][d] chunk-swizzled
  __shared__ unsigned short Vs[2][64 * 64]; // [d][j] chunk-swizzled
  __shared__ float El[4][16 * 89];          // per-wave E window [qloc][c]
  __shared__ unsigned short Pl[4][16 * 64]; // per-wave P^T-as-B [q][j] chunk-swizzled

  const int id = blockIdx.x;
  const int g = id >> 4, h = id & 15;
  const int qb = (g < 16) ? (31 - g) : (g - 16);   // pair long+short
  const int q0 = qb << 6;
  const int tid = threadIdx.x;
  const int w = tid >> 6, lane = tid & 63;
  const int lid = lane & 15, lgrp = lane >> 4;
  const int sr = lane >> 3;
  const int scc = (lane & 7) ^ sr;

  // loop-invariant fragments
  bf16x8 qf[2];
  #pragma unroll
  for (int kk = 0; kk < 2; ++kk)
    qf[kk] = *(const bf16x8*)(Y + (size_t)(q0 + w*16 + lid) * LDY2 + h*64 + ((kk*4 + lgrp) << 3));

  bf16x8 rf = {};
  {
    const unsigned* rp = (const unsigned*)(Y + (size_t)(q0 + w*16 + lid) * LDY2 + 3072 + h*10);
    if (lgrp == 0){
      #pragma unroll
      for (int x = 0; x < 4; ++x) ((unsigned*)&rf)[x] = rp[x];
    } else if (lgrp == 1){
      ((unsigned*)&rf)[0] = rp[4];
    }
  }

  float m_i = -INFINITY, l_i = 0.f;
  f32x4 o[4] = {};
  float* el = &El[w][0];
  unsigned short* pw = &Pl[w][0];

  // prologue: stage tile 0 into buffer 0
  {
    #pragma unroll
    for (int it = 0; it < 2; ++it){
      const int r0w = (w << 4) + (it << 3);
      const int r = r0w + sr;
      __builtin_amdgcn_global_load_lds(GLB(Y  + (size_t)r * LDY2 + 1024 + h*64 + (scc << 3)),
                                       LDSP(&Ks[0][r0w << 6]), 16, 0, 0);
      __builtin_amdgcn_global_load_lds(GLB(Vt + (size_t)(h*64 + r) * 2048 + (scc << 3)),
                                       LDSP(&Vs[0][r0w << 6]), 16, 0, 0);
    }
  }
  __syncthreads();

  int cur = 0;
  for (int kb = 0; kb <= qb; ++kb){
    const int j0 = kb << 6, d0 = q0 - j0;

    // stage next tile into the other buffer (hidden under this iter's compute)
    if (kb < qb){
      const int jn = j0 + 64;
      #pragma unroll
      for (int it = 0; it < 2; ++it){
        const int r0w = (w << 4) + (it << 3);
        const int r = r0w + sr;
        __builtin_amdgcn_global_load_lds(GLB(Y  + (size_t)(jn + r) * LDY2 + 1024 + h*64 + (scc << 3)),
                                         LDSP(&Ks[cur ^ 1][r0w << 6]), 16, 0, 0);
        __builtin_amdgcn_global_load_lds(GLB(Vt + (size_t)(h*64 + r) * 2048 + jn + (scc << 3)),
                                         LDSP(&Vs[cur ^ 1][r0w << 6]), 16, 0, 0);
      }
    }

    // issue BndT loads early (latency overlaps the S-MFMAs below)
    bf16x8 bw[5];
    #pragma unroll
    for (int f = 0; f < 5; ++f){
      const int rowt = d0 + 1 + (w + f) * 16 + lid;     // rel + 64
      bw[f] = *(const bf16x8*)(BndT + ((size_t)rowt << 5) + (lgrp << 3));
    }

    // S^T = K Q^T : s[n4][i] = S[q=lid][j = n4*16 + lgrp*4 + i]
    f32x4 s[4] = {};
    __builtin_amdgcn_s_setprio(1);
    #pragma unroll
    for (int kk = 0; kk < 2; ++kk){
      const int kc = kk * 4 + lgrp;
      #pragma unroll
      for (int n4 = 0; n4 < 4; ++n4){
        const bf16x8 kf = *(const bf16x8*)&Ks[cur][((n4*16 + lid) << 6) + ((kc ^ (lid & 7)) << 3)];
        s[n4] = MFMA16(kf, qf[kk], s[n4]);
      }
    }
    __builtin_amdgcn_s_setprio(0);

    // E window via MFMA (wave-local LDS, no barrier)
    // store column f*16+lid (value row rowt = d0+1+(w+f)*16+lid  ⇒ rel = d0 + w*16 + (f*16+lid) - 63)
    #pragma unroll
    for (int f = 0; f < 5; ++f){
      f32x4 ef = {};
      ef = MFMA16(rf, bw[f], ef);
      #pragma unroll
      for (int i = 0; i < 4; ++i)
        el[(lgrp*4 + i) * 89 + f*16 + lid] = ef[i];
    }

    // + bias gather + causal mask
    const bool diag = (kb == qb);
    const int ql = w*16 + lid;
    #pragma unroll
    for (int n4 = 0; n4 < 4; ++n4){
      #pragma unroll
      for (int i = 0; i < 4; ++i){
        const int jl = n4*16 + lgrp*4 + i;
        float v = s[n4][i] + el[lid * 89 + (lid - jl + 63)];
        if (diag && jl > ql) v = -1e9f;
        s[n4][i] = v;
      }
    }

    // in-register online softmax (per-lane row q = lid), defer-max THR=8
    float rm = s[0][0];
    #pragma unroll
    for (int n4 = 0; n4 < 4; ++n4)
      #pragma unroll
      for (int i = 0; i < 4; ++i) rm = fmaxf(rm, s[n4][i]);
    rm = fmaxf(rm, __shfl_xor(rm, 16));
    rm = fmaxf(rm, __shfl_xor(rm, 32));

    if (__all(rm - m_i <= 8.f)){
      // keep old max: P bounded by e^8, no o-rescale
      float rs = 0.f;
      #pragma unroll
      for (int n4 = 0; n4 < 4; ++n4)
        #pragma unroll
        for (int i = 0; i < 4; ++i){
          const float p = __expf(s[n4][i] - m_i);
          s[n4][i] = p;
          rs += p;
        }
      rs += __shfl_xor(rs, 16);
      rs += __shfl_xor(rs, 32);
      l_i += rs;
    } else {
      const float mn = fmaxf(m_i, rm);
      const float sc_ = __expf(m_i - mn);
      m_i = mn;
      float rs = 0.f;
      #pragma unroll
      for (int n4 = 0; n4 < 4; ++n4)
        #pragma unroll
        for (int i = 0; i < 4; ++i){
          const float p = __expf(s[n4][i] - mn);
          s[n4][i] = p;
          rs += p;
        }
      rs += __shfl_xor(rs, 16);
      rs += __shfl_xor(rs, 32);
      l_i = l_i * sc_ + rs;
      #pragma unroll
      for (int n4 = 0; n4 < 4; ++n4)
        #pragma unroll
        for (int i = 0; i < 4; ++i) o[n4][i] *= sc_;
    }

    // P -> wave-local LDS as B-operand rows [q=lid][j], chunk-XOR swizzle
    #pragma unroll
    for (int n4 = 0; n4 < 4; ++n4){
      const unsigned a = ((unsigned)f2bf_rn(s[n4][0])) | (((unsigned)f2bf_rn(s[n4][1])) << 16);
      const unsigned b = ((unsigned)f2bf_rn(s[n4][2])) | (((unsigned)f2bf_rn(s[n4][3])) << 16);
      const int chunk = (n4*2 + (lgrp >> 1)) ^ (lid & 7);
      const int base = (lid << 6) + (chunk << 3) + ((lgrp & 1) << 2);
      *(unsigned*)&pw[base]     = a;
      *(unsigned*)&pw[base + 2] = b;
    }

    // O^T += V^T P^T
    __builtin_amdgcn_s_setprio(1);
    #pragma unroll
    for (int kk = 0; kk < 2; ++kk){
      const int kc = kk * 4 + lgrp;
      const bf16x8 pb = *(const bf16x8*)&pw[(lid << 6) + ((kc ^ (lid & 7)) << 3)];
      #pragma unroll
      for (int n4 = 0; n4 < 4; ++n4){
        const bf16x8 vf = *(const bf16x8*)&Vs[cur][((n4*16 + lid) << 6) + ((kc ^ (lid & 7)) << 3)];
        o[n4] = MFMA16(vf, pb, o[n4]);
      }
    }
    __builtin_amdgcn_s_setprio(0);

    __syncthreads();   // next tile fully staged; safe to swap buffers
    cur ^= 1;
  }

  // epilogue: O^T[d][q=lid] -> AO[q][h*64+d], 8B packed stores
  const float inv = 1.f / l_i;
  unsigned short* dst = AO + (size_t)(q0 + w*16 + lid) * 1024 + h * 64;
  #pragma unroll
  for (int n4 = 0; n4 < 4; ++n4){
    unsigned r0 = ((unsigned)f2bf_rn(o[n4][0] * inv)) | (((unsigned)f2bf_rn(o[n4][1] * inv)) << 16);
    unsigned r1 = ((unsigned)f2bf_rn(o[n4][2] * inv)) | (((unsigned)f2bf_rn(o[n4][3] * inv)) << 16);
    unsigned long long pk = ((unsigned long long)r1 << 32) | r0;
    *(unsigned long long*)(dst + n4*16 + lgrp*4) = pk;
  }
}

// ---------------- launch ----------------

extern "C" void kernel_launch(void* const* d_in, const int* in_sizes, int n_in,
                              void* d_out, int out_size, void* d_ws, size_t ws_size,
                              hipStream_t stream) {
  const float* X   = (const float*)d_in[0];
  const float* Wq  = (const float*)d_in[1];
  const float* bq  = (const float*)d_in[2];
  const float* Wk  = (const float*)d_in[3];
  const float* Wv  = (const float*)d_in[4];
  const float* Wp  = (const float*)d_in[5];
  const float* bp  = (const float*)d_in[6];
  const float* Wr  = (const float*)d_in[7];
  const float* br  = (const float*)d_in[8];
  const float* bnd = (const float*)d_in[9];
  float* out = (float*)d_out;

  unsigned short* Xb  = (unsigned short*)d_ws;            // 2048*1024 (reused as AO)
  unsigned short* WbT = Xb  + (size_t)2048 * 1024;        // 3328*1024 (BndT alias after gemm)
  unsigned short* Yb  = WbT + (size_t)3328 * 1024;        // 2048*3328
  unsigned short* Vt  = Yb  + (size_t)2048 * 3328;        // 1024*2048
  unsigned short* WpT = Vt  + (size_t)1024 * 2048;        // 1024*1024
  float* bias = (float*)(WpT + (size_t)1024 * 1024);      // 3328
  unsigned short* AO   = Xb;    // Xb dead after projection GEMM
  unsigned short* BndT = WbT;   // WbT dead after projection GEMM

  convert_x   <<<1024,         256, 0, stream>>>(X, Xb);
  pack_wbt    <<<dim3(16, 52), 256, 0, stream>>>(Wq, Wk, Wv, Wr, WbT);
  transpose_wp<<<dim3(16, 16), 256, 0, stream>>>(Wp, WpT);
  build_bias  <<<13,           256, 0, stream>>>(bq, br, bias);

  gemm_bf16   <<<dim3(26, 16), 256, 0, stream>>>(Xb, WbT, bias, Yb, 3328, 0);
  vt_transpose<<<dim3(32, 16), 256, 0, stream>>>(Yb, Vt);
  build_bndt  <<<9,            256, 0, stream>>>(bnd, BndT);
  attn_mfma   <<<512,          256, 0, stream>>>(Yb, Vt, BndT, AO);
  gemm_bf16   <<<dim3(8, 16),  256, 0, stream>>>(AO, WpT, bp, out, 1024, 1);
}